// Round 1
// baseline (3522.157 us; speedup 1.0000x reference)
//
#include <hip/hip_runtime.h>

#define FDIM 100
#define SEQ 101
#define DIM 32
#define DEPTH 6
#define HEADS 8
#define DH 16
#define INNER 128
#define HIDN 100
#define FFH 128
#define FYH 1000
#define LN_EPS 1e-5f

typedef _Float16 f16;

// LDS plan (bytes):
//  Z   [101][33] f32 = 13332
//  Y   [101][33] f32 = 13332
//  U   (union)       = 30528
//    attn: Qb[101][16]f16 @0 (3232) | Kb[101][18]f16 @3232 (3636)
//          Vb[101][16]f16 @6868 (3232) | Ab[101][101]f16 @10112 (20402)
//          Ob aliases Qb (Qb dead after logits stage)
//    ff  : Hb[101][128]f16 @0 (25856)
//  total = 57208 B  -> 2 blocks/CU

__global__ __launch_bounds__(256) void saint_fused(
    const float* __restrict__ x,
    const float* __restrict__ mlp_w1,
    const float* __restrict__ mlp_b1,
    const float* __restrict__ mlp_w2,
    const float* __restrict__ mlp_b2,
    const float* __restrict__ mask_emb,
    const float* __restrict__ cat_emb,
    const float* __restrict__ ln1_g,
    const float* __restrict__ ln1_b,
    const float* __restrict__ wqkv,
    const float* __restrict__ wout,
    const float* __restrict__ bout,
    const float* __restrict__ ln2_g,
    const float* __restrict__ ln2_b,
    const float* __restrict__ ff_w1,
    const float* __restrict__ ff_b1,
    const float* __restrict__ ff_w2,
    const float* __restrict__ ff_b2,
    const float* __restrict__ fy_w1,
    const float* __restrict__ fy_b1,
    const float* __restrict__ fy_w2,
    const float* __restrict__ fy_b2,
    float* __restrict__ out)
{
  __shared__ float Z[SEQ][33];
  __shared__ float Y[SEQ][33];
  __shared__ __align__(16) char U[30528];
  __shared__ float red[4];

  f16* Qb = (f16*)&U[0];       // [101][16]
  f16* Kb = (f16*)&U[3232];    // [101][18] (pad: odd word stride -> no bank conflict)
  f16* Vb = (f16*)&U[6868];    // [101][16]
  f16* Ab = (f16*)&U[10112];   // [101][101]
  f16* Ob = (f16*)&U[0];       // alias of Qb
  f16* Hb = (f16*)&U[0];       // [101][128] (FF phase only)

  const int b = blockIdx.x;
  const int tid = threadIdx.x;
  const int lane = tid & 63;
  const int wid = tid >> 6;

  // ---------------- feature-embed MLP ----------------
  {
    const int d = tid & 31, grp = tid >> 5;
    if (tid < DIM) {
      int ci = (int)x[(size_t)b * SEQ];       // x[:,0] == 0
      Z[0][tid] = cat_emb[ci * DIM + tid];
    }
    for (int f = grp; f < FDIM; f += 8) {
      float xv = x[(size_t)b * SEQ + 1 + f];
      float acc;
      if (xv != xv) {                          // NaN -> mask embedding, idx = 2*f
        acc = mask_emb[(2 * f) * DIM + d];
      } else {
        acc = mlp_b2[f * DIM + d];
        const float* w1 = mlp_w1 + f * HIDN;
        const float* b1 = mlp_b1 + f * HIDN;
        const float* w2 = mlp_w2 + (size_t)f * HIDN * DIM + d;
        #pragma unroll 4
        for (int j = 0; j < HIDN; ++j) {
          float h = fmaxf(fmaf(xv, w1[j], b1[j]), 0.f);
          acc = fmaf(h, w2[(size_t)j * DIM], acc);
        }
      }
      Z[1 + f][d] = acc;
    }
  }
  __syncthreads();

  for (int l = 0; l < DEPTH; ++l) {
    // ---- LN1: Z -> Y ----
    {
      const int d = tid & 31, sg = tid >> 5;
      const float gv = ln1_g[l * DIM + d], bv = ln1_b[l * DIM + d];
      for (int s = sg; s < SEQ; s += 8) {
        float v = Z[s][d];
        float m = v;
        #pragma unroll
        for (int off = 16; off; off >>= 1) m += __shfl_xor(m, off, 32);
        m *= 0.03125f;
        float cv = v - m;
        float vr = cv * cv;
        #pragma unroll
        for (int off = 16; off; off >>= 1) vr += __shfl_xor(vr, off, 32);
        vr *= 0.03125f;
        Y[s][d] = cv * rsqrtf(vr + LN_EPS) * gv + bv;
      }
    }
    __syncthreads();

    // ---- attn residual init: Z = Y + bout (same thread->(s,c) map as proj stage) ----
    {
      const int d = tid & 31, sg = tid >> 5;
      const float bo = bout[l * DIM + d];
      for (int s = sg; s < SEQ; s += 8) Z[s][d] = Y[s][d] + bo;
    }

    // ---- attention, head by head ----
    for (int h = 0; h < HEADS; ++h) {
      __syncthreads();  // prev head's proj (reads Ob) done before Qb overwritten
      // QKV for head h: Y(101x32) @ wqkv slices
      {
        const int dd = tid & 15, gg = tid >> 4;
        const float* wl = wqkv + (size_t)l * DIM * (3 * INNER) + h * DH + dd;
        for (int s = gg; s < SEQ; s += 16) {
          float aq = 0.f, ak = 0.f, av = 0.f;
          #pragma unroll
          for (int c = 0; c < DIM; ++c) {
            float yv = Y[s][c];
            aq = fmaf(yv, wl[c * 384], aq);
            ak = fmaf(yv, wl[c * 384 + 128], ak);
            av = fmaf(yv, wl[c * 384 + 256], av);
          }
          Qb[s * 16 + dd] = (f16)aq;
          Kb[s * 18 + dd] = (f16)ak;
          Vb[s * 16 + dd] = (f16)av;
        }
      }
      __syncthreads();
      // logits: A[s][j] = 0.25 * Q[s].K[j]; 4 j-columns per thread (K rows in regs)
      {
        const int jj = tid & 31, sg = tid >> 5;
        const bool c4 = (jj < 5);
        float k0[DH], k1[DH], k2[DH], k3[DH];
        #pragma unroll
        for (int d = 0; d < DH; ++d) {
          k0[d] = (float)Kb[jj * 18 + d];
          k1[d] = (float)Kb[(jj + 32) * 18 + d];
          k2[d] = (float)Kb[(jj + 64) * 18 + d];
          k3[d] = c4 ? (float)Kb[(jj + 96) * 18 + d] : 0.f;
        }
        for (int s = sg; s < SEQ; s += 8) {
          float a0 = 0.f, a1 = 0.f, a2 = 0.f, a3 = 0.f;
          #pragma unroll
          for (int d = 0; d < DH; ++d) {
            float qv = (float)Qb[s * 16 + d];
            a0 = fmaf(qv, k0[d], a0);
            a1 = fmaf(qv, k1[d], a1);
            a2 = fmaf(qv, k2[d], a2);
            a3 = fmaf(qv, k3[d], a3);
          }
          const int base = s * 101;
          Ab[base + jj]      = (f16)(a0 * 0.25f);
          Ab[base + jj + 32] = (f16)(a1 * 0.25f);
          Ab[base + jj + 64] = (f16)(a2 * 0.25f);
          if (c4) Ab[base + jj + 96] = (f16)(a3 * 0.25f);
        }
      }
      __syncthreads();
      // softmax over each row of A (32 lanes per row, fp32 math, f16 store)
      {
        const int sl = tid & 31, sg = tid >> 5;
        const bool h4 = (sl < 5);
        for (int s = sg; s < SEQ; s += 8) {
          const int base = s * 101;
          float v0 = (float)Ab[base + sl];
          float v1 = (float)Ab[base + 32 + sl];
          float v2 = (float)Ab[base + 64 + sl];
          float v3 = h4 ? (float)Ab[base + 96 + sl] : -1e30f;
          float mx = fmaxf(fmaxf(v0, v1), fmaxf(v2, v3));
          #pragma unroll
          for (int off = 16; off; off >>= 1) mx = fmaxf(mx, __shfl_xor(mx, off, 32));
          float e0 = __expf(v0 - mx), e1 = __expf(v1 - mx), e2 = __expf(v2 - mx);
          float e3 = h4 ? __expf(v3 - mx) : 0.f;
          float sm = e0 + e1 + e2 + e3;
          #pragma unroll
          for (int off = 16; off; off >>= 1) sm += __shfl_xor(sm, off, 32);
          float inv = 1.f / sm;
          Ab[base + sl]      = (f16)(e0 * inv);
          Ab[base + 32 + sl] = (f16)(e1 * inv);
          Ab[base + 64 + sl] = (f16)(e2 * inv);
          if (h4) Ab[base + 96 + sl] = (f16)(e3 * inv);
        }
      }
      __syncthreads();
      // O = A @ V  (writes Ob, aliasing dead Qb)
      {
        const int dd = tid & 15, sg = tid >> 4;
        const bool r7 = (sg < 5);
        float acc[7];
        #pragma unroll
        for (int r = 0; r < 7; ++r) acc[r] = 0.f;
        for (int j = 0; j < SEQ; ++j) {
          float vv = (float)Vb[j * 16 + dd];
          #pragma unroll
          for (int r = 0; r < 6; ++r)
            acc[r] = fmaf((float)Ab[(sg + r * 16) * 101 + j], vv, acc[r]);
          if (r7) acc[6] = fmaf((float)Ab[(sg + 96) * 101 + j], vv, acc[6]);
        }
        #pragma unroll
        for (int r = 0; r < 6; ++r) Ob[(sg + r * 16) * 16 + dd] = (f16)acc[r];
        if (r7) Ob[(sg + 96) * 16 + dd] = (f16)acc[6];
      }
      __syncthreads();
      // Z += O_h @ wout_h
      {
        const int c = tid & 31, sg = tid >> 5;
        const float* wo = wout + ((size_t)l * INNER + h * DH) * DIM + c;
        for (int s = sg; s < SEQ; s += 8) {
          float acc = 0.f;
          #pragma unroll
          for (int d = 0; d < DH; ++d)
            acc = fmaf((float)Ob[s * 16 + d], wo[d * DIM], acc);
          Z[s][c] += acc;
        }
      }
    }
    __syncthreads();

    // ---- LN2: Z -> Y ----
    {
      const int d = tid & 31, sg = tid >> 5;
      const float gv = ln2_g[l * DIM + d], bv = ln2_b[l * DIM + d];
      for (int s = sg; s < SEQ; s += 8) {
        float v = Z[s][d];
        float m = v;
        #pragma unroll
        for (int off = 16; off; off >>= 1) m += __shfl_xor(m, off, 32);
        m *= 0.03125f;
        float cv = v - m;
        float vr = cv * cv;
        #pragma unroll
        for (int off = 16; off; off >>= 1) vr += __shfl_xor(vr, off, 32);
        vr *= 0.03125f;
        Y[s][d] = cv * rsqrtf(vr + LN_EPS) * gv + bv;
      }
    }
    __syncthreads();

    // ---- FF hidden: Hb = gelu(Y @ ff_w1 + b1)  (exact gelu) ----
    {
      const int jj = tid & 127, half = tid >> 7;
      float w1r[DIM];
      #pragma unroll
      for (int c = 0; c < DIM; ++c) w1r[c] = ff_w1[((size_t)l * DIM + c) * FFH + jj];
      const float b1v = ff_b1[l * FFH + jj];
      for (int s = half; s < SEQ; s += 2) {
        float acc = b1v;
        #pragma unroll
        for (int c = 0; c < DIM; ++c) acc = fmaf(Y[s][c], w1r[c], acc);
        float ge = 0.5f * acc * (1.f + erff(acc * 0.70710678118654752440f));
        Hb[s * FFH + jj] = (f16)ge;
      }
    }
    __syncthreads();
    // ---- FF out + residual: Z = Y + Hb @ ff_w2 + b2 ----
    {
      const int c = tid & 31, sg = tid >> 5;
      const bool r13 = (sg < 5);
      const float* w2 = ff_w2 + (size_t)l * FFH * DIM + c;
      float acc[13];
      #pragma unroll
      for (int r = 0; r < 13; ++r) acc[r] = 0.f;
      for (int j = 0; j < FFH; ++j) {
        float w2v = w2[j * DIM];
        #pragma unroll
        for (int r = 0; r < 12; ++r)
          acc[r] = fmaf((float)Hb[(sg + r * 8) * FFH + j], w2v, acc[r]);
        if (r13) acc[12] = fmaf((float)Hb[(sg + 96) * FFH + j], w2v, acc[12]);
      }
      const float b2v = ff_b2[l * DIM + c];
      #pragma unroll
      for (int r = 0; r < 12; ++r) {
        int s = sg + r * 8;
        Z[s][c] = Y[s][c] + acc[r] + b2v;
      }
      if (r13) Z[sg + 96][c] = Y[sg + 96][c] + acc[12] + b2v;
    }
    __syncthreads();
  }

  // ---------------- final head: out[b] = relu(z0 @ fy_w1 + b1) @ fy_w2 + b2 ----------------
  {
    float part = 0.f;
    for (int j = tid; j < FYH; j += 256) {
      float acc = fy_b1[j];
      #pragma unroll
      for (int c = 0; c < DIM; ++c) acc = fmaf(Z[0][c], fy_w1[c * FYH + j], acc);
      part += fmaxf(acc, 0.f) * fy_w2[j];
    }
    #pragma unroll
    for (int off = 32; off; off >>= 1) part += __shfl_xor(part, off, 64);
    if (lane == 0) red[wid] = part;
    __syncthreads();
    if (tid == 0) out[b] = red[0] + red[1] + red[2] + red[3] + fy_b2[0];
  }
}

extern "C" void kernel_launch(void* const* d_in, const int* in_sizes, int n_in,
                              void* d_out, int out_size, void* d_ws, size_t ws_size,
                              hipStream_t stream) {
  (void)in_sizes; (void)n_in; (void)d_ws; (void)ws_size; (void)out_size;
  saint_fused<<<dim3(1024), dim3(256), 0, stream>>>(
      (const float*)d_in[0],  (const float*)d_in[1],  (const float*)d_in[2],
      (const float*)d_in[3],  (const float*)d_in[4],  (const float*)d_in[5],
      (const float*)d_in[6],  (const float*)d_in[7],  (const float*)d_in[8],
      (const float*)d_in[9],  (const float*)d_in[10], (const float*)d_in[11],
      (const float*)d_in[12], (const float*)d_in[13], (const float*)d_in[14],
      (const float*)d_in[15], (const float*)d_in[16], (const float*)d_in[17],
      (const float*)d_in[18], (const float*)d_in[19], (const float*)d_in[20],
      (const float*)d_in[21], (float*)d_out);
}

// Round 2
// 643.849 us; speedup vs baseline: 5.4705x; 5.4705x over previous
//
#include <hip/hip_runtime.h>

#define FDIM 100
#define SEQ 101
#define DIM 32
#define DEPTH 6
#define HEADS 8
#define DH 16
#define INNER 128
#define HIDN 100
#define FFH 128
#define FYH 1000
#define LN_EPS 1e-5f

typedef _Float16 f16;
typedef __attribute__((ext_vector_type(4))) _Float16 f16x4;
typedef __attribute__((ext_vector_type(4))) float f32x4;

// LDS strides (elements)
#define ZSTR 36   // Z fp32 [104][36]
#define YSTR 36   // Yh f16 [112][36]
#define QSTR 20   // Qb/Kb f16 [112][20]
#define VSTR 116  // Vt f16 [16][116]
#define HSTR 132  // Hs f16 [112][132]

// MFMA 16x16x16 f16 lane layout (classic CDNA):
//  A-frag: lane l holds A[m0 + (l&15)][k0 + 4*(l>>4) + i], i=0..3
//  B-frag: lane l holds B[k0 + 4*(l>>4) + i][n0 + (l&15)]
//  D:      lane l reg r holds D[m0 + 4*(l>>4) + r][n0 + (l&15)]

__device__ __forceinline__ f32x4 mfma16(f16x4 a, f16x4 b, f32x4 c) {
  return __builtin_amdgcn_mfma_f32_16x16x16f16(a, b, c, 0, 0, 0);
}
__device__ __forceinline__ f16x4 pack4(f32x4 v) {
  f16x4 r;
  r[0] = (f16)v[0]; r[1] = (f16)v[1]; r[2] = (f16)v[2]; r[3] = (f16)v[3];
  return r;
}

__global__ __launch_bounds__(256, 3) void saint_mfma(
    const float* __restrict__ x,
    const float* __restrict__ mlp_w1,
    const float* __restrict__ mlp_b1,
    const float* __restrict__ mlp_w2,
    const float* __restrict__ mlp_b2,
    const float* __restrict__ mask_emb,
    const float* __restrict__ cat_emb,
    const float* __restrict__ ln1_g,
    const float* __restrict__ ln1_b,
    const float* __restrict__ wqkv,
    const float* __restrict__ wout,
    const float* __restrict__ bout,
    const float* __restrict__ ln2_g,
    const float* __restrict__ ln2_b,
    const float* __restrict__ ff_w1,
    const float* __restrict__ ff_b1,
    const float* __restrict__ ff_w2,
    const float* __restrict__ ff_b2,
    const float* __restrict__ fy_w1,
    const float* __restrict__ fy_b1,
    const float* __restrict__ fy_w2,
    const float* __restrict__ fy_b2,
    float* __restrict__ out)
{
  __shared__ float Z[104][ZSTR];       // 14976 B (fp32 residual stream)
  __shared__ f16  Yh[112][YSTR];       //  8064 B (f16 LN output, MFMA operand)
  __shared__ float row_m[104], row_r[104];  // 832 B (LN stats for residual recompute)
  __shared__ __align__(16) char Ubuf[2 * HSTR * 112];  // 29568 B union
  __shared__ float red[4];

  f16* const Qb = (f16*)Ubuf;                  // [112][20]
  f16* const Kb = (f16*)(Ubuf + 4480);         // [112][20]
  f16* const Vt = (f16*)(Ubuf + 8960);         // [16][116]
  f16* const Hs = (f16*)Ubuf;                  // [112][132] (FF phase)

  const int b = blockIdx.x;
  const int tid = threadIdx.x;
  const int lane = tid & 63;
  const int wid = tid >> 6;     // wave id 0..3
  const int l15 = lane & 15;
  const int l4 = lane >> 4;     // 0..3

  const f32x4 zero4 = {0.f, 0.f, 0.f, 0.f};

  // ---- zero Yh pad rows (101..111) once; they stay zero forever ----
  for (int i = tid; i < 11 * YSTR; i += 256) {
    Yh[101 + i / YSTR][i % YSTR] = (f16)0.f;
  }

  // ---------------- feature-embed MLP ----------------
  {
    const int d = tid & 31, grp = tid >> 5;
    if (tid < DIM) {
      int ci = (int)x[(size_t)b * SEQ];       // x[:,0] == 0
      Z[0][tid] = cat_emb[ci * DIM + tid];
    }
    for (int f = grp; f < FDIM; f += 8) {
      float xv = x[(size_t)b * SEQ + 1 + f];
      float acc;
      if (xv != xv) {                          // NaN -> mask embedding (idx 2f)
        acc = mask_emb[(2 * f) * DIM + d];
      } else {
        acc = mlp_b2[f * DIM + d];
        const float* w1 = mlp_w1 + f * HIDN;
        const float* b1 = mlp_b1 + f * HIDN;
        const float* w2 = mlp_w2 + (size_t)f * HIDN * DIM + d;
        #pragma unroll 4
        for (int j = 0; j < HIDN; ++j) {
          float h = fmaxf(fmaf(xv, w1[j], b1[j]), 0.f);
          acc = fmaf(h, w2[(size_t)j * DIM], acc);
        }
      }
      Z[1 + f][d] = acc;
    }
  }
  __syncthreads();

  for (int l = 0; l < DEPTH; ++l) {
    // ---- LN1: Z -> Yh (f16) + rowstats ----
    {
      const int d = tid & 31, sg = tid >> 5;
      const float gv = ln1_g[l * DIM + d], bv = ln1_b[l * DIM + d];
      for (int s = sg; s < SEQ; s += 8) {
        float v = Z[s][d];
        float m = v;
        #pragma unroll
        for (int off = 16; off; off >>= 1) m += __shfl_xor(m, off, 32);
        m *= 0.03125f;
        float cv = v - m;
        float vr = cv * cv;
        #pragma unroll
        for (int off = 16; off; off >>= 1) vr += __shfl_xor(vr, off, 32);
        float rs = rsqrtf(vr * 0.03125f + LN_EPS);
        Yh[s][d] = (f16)(cv * rs * gv + bv);
        if (d == 0) { row_m[s] = m; row_r[s] = rs; }
      }
    }
    __syncthreads();

    // ---- attention: projection accumulators (per wave, per its s-tiles) ----
    f32x4 zp[2][2];   // [ct][t] — accessed only with unrolled (constant) indices
    zp[0][0] = zero4; zp[0][1] = zero4; zp[1][0] = zero4; zp[1][1] = zero4;

    for (int h = 0; h < HEADS; ++h) {
      // -- head weight fragments from global (L2-hot) --
      const float* wq = wqkv + (size_t)l * (DIM * 3 * INNER) + h * DH + l15;
      f16x4 aQ[2], aK[2], bV[2];
      #pragma unroll
      for (int kk = 0; kk < 2; ++kk) {
        #pragma unroll
        for (int i = 0; i < 4; ++i) {
          const float* p = wq + (kk * 16 + 4 * l4 + i) * 384;
          aQ[kk][i] = (f16)(p[0] * 0.25f);   // fold DH^-0.5 into Q weights
          aK[kk][i] = (f16)p[128];
          bV[kk][i] = (f16)p[256];
        }
      }
      // -- step 1: QKV tiles for this wave's s-tiles --
      #pragma unroll
      for (int t = 0; t < 2; ++t) {
        const int ns = wid + 4 * t;
        if (ns < 7) {
          const int s = ns * 16 + l15;
          f16x4 y0 = *(const f16x4*)&Yh[s][4 * l4];
          f16x4 y1 = *(const f16x4*)&Yh[s][16 + 4 * l4];
          f32x4 dQ = zero4, dK = zero4, dV = zero4;
          dQ = mfma16(aQ[0], y0, dQ); dQ = mfma16(aQ[1], y1, dQ);  // Q^T[d][s]
          dK = mfma16(aK[0], y0, dK); dK = mfma16(aK[1], y1, dK);  // K^T[d][s]
          dV = mfma16(y0, bV[0], dV); dV = mfma16(y1, bV[1], dV);  // V[s][d]
          *(f16x4*)&Qb[s * QSTR + 4 * l4] = pack4(dQ);
          *(f16x4*)&Kb[s * QSTR + 4 * l4] = pack4(dK);
          *(f16x4*)&Vt[l15 * VSTR + ns * 16 + 4 * l4] = pack4(dV);
        }
      }
      __syncthreads();

      // -- K / V^T fragments (reused across this wave's s-tiles) --
      f16x4 aKf[7], aVf[7];
      #pragma unroll
      for (int jt = 0; jt < 7; ++jt) {
        aKf[jt] = *(const f16x4*)&Kb[(jt * 16 + l15) * QSTR + 4 * l4];
        aVf[jt] = *(const f16x4*)&Vt[l15 * VSTR + jt * 16 + 4 * l4];
      }
      // woutT fragments
      const float* wo = wout + (size_t)l * (INNER * DIM) + (h * DH + 4 * l4) * DIM + l15;
      f16x4 aW0, aW1;
      #pragma unroll
      for (int i = 0; i < 4; ++i) {
        aW0[i] = (f16)wo[i * DIM];
        aW1[i] = (f16)wo[i * DIM + 16];
      }

      // -- steps 2-5 per s-tile: logits -> softmax -> AV -> proj --
      #pragma unroll
      for (int t = 0; t < 2; ++t) {
        const int ns = wid + 4 * t;
        if (ns < 7) {
          f16x4 bQ = *(const f16x4*)&Qb[(ns * 16 + l15) * QSTR + 4 * l4];
          f32x4 L[7];
          #pragma unroll
          for (int jt = 0; jt < 7; ++jt) L[jt] = mfma16(aKf[jt], bQ, zero4);
          // mask j > 100 (tile 6: j = 96 + 4*l4 + r)
          #pragma unroll
          for (int r = 0; r < 4; ++r)
            if (4 * l4 + r > 4) L[6][r] = -1e30f;
          float mx = -1e30f;
          #pragma unroll
          for (int jt = 0; jt < 7; ++jt) {
            #pragma unroll
            for (int r = 0; r < 4; ++r) mx = fmaxf(mx, L[jt][r]);
          }
          mx = fmaxf(mx, __shfl_xor(mx, 16));
          mx = fmaxf(mx, __shfl_xor(mx, 32));
          float sum = 0.f;
          f16x4 bP[7];
          #pragma unroll
          for (int jt = 0; jt < 7; ++jt) {
            f32x4 e;
            #pragma unroll
            for (int r = 0; r < 4; ++r) {
              e[r] = __expf(L[jt][r] - mx);
              sum += e[r];
            }
            bP[jt] = pack4(e);   // unnormalized P^T frag (values <= 1)
          }
          sum += __shfl_xor(sum, 16);
          sum += __shfl_xor(sum, 32);
          const float inv = 1.f / sum;
          f32x4 O = zero4;
          #pragma unroll
          for (int jt = 0; jt < 7; ++jt) O = mfma16(aVf[jt], bP[jt], O);  // O^T[d][s]
          f16x4 bO;
          #pragma unroll
          for (int r = 0; r < 4; ++r) bO[r] = (f16)(O[r] * inv);
          zp[0][t] = mfma16(aW0, bO, zp[0][t]);   // Zp^T[c][s], c-tile 0
          zp[1][t] = mfma16(aW1, bO, zp[1][t]);   // c-tile 1
        }
      }
      __syncthreads();
    }

    // ---- attn residual: Z[s][c] = LN1(Z) + bout + proj  (in-place, fp32) ----
    {
      #pragma unroll
      for (int t = 0; t < 2; ++t) {
        const int ns = wid + 4 * t;
        if (ns < 7) {
          const int s = ns * 16 + l15;
          if (s < SEQ) {
            const float m = row_m[s], rs = row_r[s];
            #pragma unroll
            for (int ct = 0; ct < 2; ++ct) {
              const int c0 = ct * 16 + 4 * l4;
              const f32x4 gv = *(const f32x4*)(ln1_g + l * DIM + c0);
              const f32x4 bv = *(const f32x4*)(ln1_b + l * DIM + c0);
              const f32x4 bo = *(const f32x4*)(bout + l * DIM + c0);
              f32x4 z = *(f32x4*)&Z[s][c0];
              #pragma unroll
              for (int r = 0; r < 4; ++r)
                z[r] = (z[r] - m) * rs * gv[r] + bv[r] + bo[r] + zp[ct][t][r];
              *(f32x4*)&Z[s][c0] = z;
            }
          }
        }
      }
    }
    __syncthreads();

    // ---- LN2: Z -> Yh + rowstats ----
    {
      const int d = tid & 31, sg = tid >> 5;
      const float gv = ln2_g[l * DIM + d], bv = ln2_b[l * DIM + d];
      for (int s = sg; s < SEQ; s += 8) {
        float v = Z[s][d];
        float m = v;
        #pragma unroll
        for (int off = 16; off; off >>= 1) m += __shfl_xor(m, off, 32);
        m *= 0.03125f;
        float cv = v - m;
        float vr = cv * cv;
        #pragma unroll
        for (int off = 16; off; off >>= 1) vr += __shfl_xor(vr, off, 32);
        float rs = rsqrtf(vr * 0.03125f + LN_EPS);
        Yh[s][d] = (f16)(cv * rs * gv + bv);
        if (d == 0) { row_m[s] = m; row_r[s] = rs; }
      }
    }
    __syncthreads();

    // ---- FF1: H^T = gelu(w1^T . Y^T + b1) -> Hs[s][j] ----
    {
      f16x4 a1[8][2];
      #pragma unroll
      for (int jt = 0; jt < 8; ++jt) {
        #pragma unroll
        for (int kk = 0; kk < 2; ++kk) {
          #pragma unroll
          for (int i = 0; i < 4; ++i)
            a1[jt][kk][i] =
                (f16)ff_w1[(size_t)l * (DIM * FFH) + (kk * 16 + 4 * l4 + i) * FFH + jt * 16 + l15];
        }
      }
      #pragma unroll
      for (int t = 0; t < 2; ++t) {
        const int ns = wid + 4 * t;
        if (ns < 7) {
          const int s = ns * 16 + l15;
          f16x4 y0 = *(const f16x4*)&Yh[s][4 * l4];
          f16x4 y1 = *(const f16x4*)&Yh[s][16 + 4 * l4];
          #pragma unroll
          for (int jt = 0; jt < 8; ++jt) {
            const f32x4 bb = *(const f32x4*)(ff_b1 + l * FFH + jt * 16 + 4 * l4);
            f32x4 d = mfma16(a1[jt][0], y0, zero4);
            d = mfma16(a1[jt][1], y1, d);
            f16x4 hv;
            #pragma unroll
            for (int r = 0; r < 4; ++r) {
              float v = d[r] + bb[r];
              hv[r] = (f16)(0.5f * v * (1.f + erff(v * 0.70710678118654752440f)));
            }
            *(f16x4*)&Hs[s * HSTR + jt * 16 + 4 * l4] = hv;
          }
        }
      }
    }
    __syncthreads();

    // ---- FF2 + residual: Z = LN2(Z)*... + w2^T.H^T + b2 ----
    {
      f16x4 a2[2][8];
      #pragma unroll
      for (int ct = 0; ct < 2; ++ct) {
        #pragma unroll
        for (int jt = 0; jt < 8; ++jt) {
          #pragma unroll
          for (int i = 0; i < 4; ++i)
            a2[ct][jt][i] =
                (f16)ff_w2[(size_t)l * (FFH * DIM) + (jt * 16 + 4 * l4 + i) * DIM + ct * 16 + l15];
        }
      }
      #pragma unroll
      for (int t = 0; t < 2; ++t) {
        const int ns = wid + 4 * t;
        if (ns < 7) {
          const int s = ns * 16 + l15;
          f16x4 bH[8];
          #pragma unroll
          for (int jt = 0; jt < 8; ++jt)
            bH[jt] = *(const f16x4*)&Hs[s * HSTR + jt * 16 + 4 * l4];
          f32x4 d0 = zero4, d1 = zero4;
          #pragma unroll
          for (int jt = 0; jt < 8; ++jt) {
            d0 = mfma16(a2[0][jt], bH[jt], d0);
            d1 = mfma16(a2[1][jt], bH[jt], d1);
          }
          if (s < SEQ) {
            const float m = row_m[s], rs = row_r[s];
            #pragma unroll
            for (int ct = 0; ct < 2; ++ct) {
              const int c0 = ct * 16 + 4 * l4;
              const f32x4 gv = *(const f32x4*)(ln2_g + l * DIM + c0);
              const f32x4 bv = *(const f32x4*)(ln2_b + l * DIM + c0);
              const f32x4 b2 = *(const f32x4*)(ff_b2 + l * DIM + c0);
              const f32x4 dd = ct ? d1 : d0;
              f32x4 z = *(f32x4*)&Z[s][c0];
              #pragma unroll
              for (int r = 0; r < 4; ++r)
                z[r] = (z[r] - m) * rs * gv[r] + bv[r] + b2[r] + dd[r];
              *(f32x4*)&Z[s][c0] = z;
            }
          }
        }
      }
    }
    __syncthreads();
  }

  // ---------------- final head ----------------
  {
    float part = 0.f;
    for (int j = tid; j < FYH; j += 256) {
      float acc = fy_b1[j];
      #pragma unroll
      for (int c = 0; c < DIM; ++c) acc = fmaf(Z[0][c], fy_w1[c * FYH + j], acc);
      part += fmaxf(acc, 0.f) * fy_w2[j];
    }
    #pragma unroll
    for (int off = 32; off; off >>= 1) part += __shfl_xor(part, off, 64);
    if (lane == 0) red[wid] = part;
    __syncthreads();
    if (tid == 0) out[b] = red[0] + red[1] + red[2] + red[3] + fy_b2[0];
  }
}

extern "C" void kernel_launch(void* const* d_in, const int* in_sizes, int n_in,
                              void* d_out, int out_size, void* d_ws, size_t ws_size,
                              hipStream_t stream) {
  (void)in_sizes; (void)n_in; (void)d_ws; (void)ws_size; (void)out_size;
  saint_mfma<<<dim3(1024), dim3(256), 0, stream>>>(
      (const float*)d_in[0],  (const float*)d_in[1],  (const float*)d_in[2],
      (const float*)d_in[3],  (const float*)d_in[4],  (const float*)d_in[5],
      (const float*)d_in[6],  (const float*)d_in[7],  (const float*)d_in[8],
      (const float*)d_in[9],  (const float*)d_in[10], (const float*)d_in[11],
      (const float*)d_in[12], (const float*)d_in[13], (const float*)d_in[14],
      (const float*)d_in[15], (const float*)d_in[16], (const float*)d_in[17],
      (const float*)d_in[18], (const float*)d_in[19], (const float*)d_in[20],
      (const float*)d_in[21], (float*)d_out);
}